// Round 4
// baseline (297578.027 us; speedup 1.0000x reference)
//
#include <hip/hip_runtime.h>
#include <math.h>

#define NB 512   // batch
#define NL 256   // seq len
#define NH 512   // hidden
#define NG 2048  // 4*H
#define NBLK 640 // persistent grid: 512 main + 128 proj

// ---------------- ws layout (float offsets) ----------------
#define WGP_ENC  ((size_t)0)          // 1,048,576  permuted gate weights [jb][kc][jj][kk]
#define WGP_DEC  ((size_t)1048576)    // 1,048,576
#define W1P_OFF  ((size_t)2097152)    // 262,144    permuted W1 [ejb][kc][jj][kk]
#define W2P_OFF  ((size_t)2359296)    // 262,144
#define A_ENC    ((size_t)2621440)    // 2048
#define D_ENC    ((size_t)2623488)    // 2048
#define A_DEC    ((size_t)2625536)    // 2048
#define D_DEC    ((size_t)2627584)    // 2048
#define BUF0     ((size_t)2629632)    // 262,144  h ping  [b][k]
#define BUF1     ((size_t)2891776)    // 262,144  h pong
#define CBUF     ((size_t)3153920)    // 262,144  c handoff enc->dec
#define QBUF     ((size_t)3416064)    // 262,144  q [b][h]
#define NXT_OFF  ((size_t)3678208)    // 512
#define BAR_OFF  ((size_t)3678720)    // 512 floats reserved (barrier counters)
#define EP_OFF   ((size_t)3679232)    // 256*512*512  enc_proj [b][l][h]
// total = 70,788,096 floats = 283.2 MB (round-2 layout of 303 MB passed, so ws fits)

__device__ __forceinline__ float fast_rcp(float x) {
  return __builtin_amdgcn_rcpf(x);
}
__device__ __forceinline__ float fast_tanh(float x) {
  x = fminf(x, 10.0f);
  float t = __expf(2.0f * x);
  return 1.0f - 2.0f * fast_rcp(t + 1.0f);
}
__device__ __forceinline__ float fast_sigmoid(float x) {
  return fast_rcp(1.0f + __expf(-x));
}

// ---------------- 2-level grid barrier (640 blocks) ----------------
// bar[i*32] i<8: leaf counters; bar[256]: root; bar[288]: generation.
__device__ __forceinline__ void gridbar(unsigned* bar) {
  __syncthreads();
  if (threadIdx.x == 0) {
    __threadfence();  // release: block's stores -> device scope
    unsigned* gen = bar + 288;
    const unsigned g = __hip_atomic_load(gen, __ATOMIC_RELAXED, __HIP_MEMORY_SCOPE_AGENT);
    const int leaf = blockIdx.x & 7;
    unsigned a = __hip_atomic_fetch_add(bar + leaf * 32, 1u, __ATOMIC_ACQ_REL,
                                        __HIP_MEMORY_SCOPE_AGENT);
    if (a == (NBLK / 8) - 1) {
      unsigned r = __hip_atomic_fetch_add(bar + 256, 1u, __ATOMIC_ACQ_REL,
                                          __HIP_MEMORY_SCOPE_AGENT);
      if (r == 7) {
#pragma unroll
        for (int i = 0; i < 8; ++i)
          __hip_atomic_store(bar + i * 32, 0u, __ATOMIC_RELAXED, __HIP_MEMORY_SCOPE_AGENT);
        __hip_atomic_store(bar + 256, 0u, __ATOMIC_RELAXED, __HIP_MEMORY_SCOPE_AGENT);
        __hip_atomic_store(gen, g + 1u, __ATOMIC_RELEASE, __HIP_MEMORY_SCOPE_AGENT);
      } else {
        while (__hip_atomic_load(gen, __ATOMIC_RELAXED, __HIP_MEMORY_SCOPE_AGENT) == g)
          __builtin_amdgcn_s_sleep(1);
      }
    } else {
      while (__hip_atomic_load(gen, __ATOMIC_RELAXED, __HIP_MEMORY_SCOPE_AGENT) == g)
        __builtin_amdgcn_s_sleep(1);
    }
    __threadfence();  // acquire: invalidate caches before reading others' data
  }
  __syncthreads();
}

// ---------------- prep kernels ----------------
// A[j] = Wih[j,:]·embW ; D[j] = Wih[j,:]·embB + bih[j] + bhh[j]
__global__ void k_prep_ad(const float* __restrict__ Wih, const float* __restrict__ embW,
                          const float* __restrict__ embB, const float* __restrict__ bih,
                          const float* __restrict__ bhh, float* __restrict__ A,
                          float* __restrict__ D) {
  const int wv = threadIdx.x >> 6, lane = threadIdx.x & 63;
  const int j = blockIdx.x * 4 + wv;
  const float* __restrict__ row = Wih + (size_t)j * NH;
  float a = 0.f, d = 0.f;
#pragma unroll
  for (int r = 0; r < 8; ++r) {
    const int k = lane + 64 * r;
    const float w = row[k];
    a = fmaf(w, embW[k], a);
    d = fmaf(w, embB[k], d);
  }
#pragma unroll
  for (int dd = 1; dd < 64; dd <<= 1) {
    a += __shfl_xor(a, dd, 64);
    d += __shfl_xor(d, dd, 64);
  }
  if (lane == 0) { A[j] = a; D[j] = d + bih[j] + bhh[j]; }
}

// WGP[jb][kc][jj][kk] = Whh[(jj&3)*512 + jb*8 + (jj>>2)][kc*128+kk]   (float4 granularity)
__global__ void k_perm_gate(const float* __restrict__ Whh, float* __restrict__ WGP) {
  const int o4 = blockIdx.x * 256 + threadIdx.x;  // 262144 float4s
  const int kq = o4 & 31, jj = (o4 >> 5) & 31, kc = (o4 >> 10) & 3, jb = o4 >> 12;
  const int r = (jj & 3) * 512 + jb * 8 + (jj >> 2);
  ((float4*)WGP)[o4] = ((const float4*)Whh)[(size_t)r * 128 + kc * 32 + kq];
}

// WP[ejb][kc][jj][kk] = W[ejb*32+jj][kc*128+kk]
__global__ void k_perm_proj(const float* __restrict__ W, float* __restrict__ WP) {
  const int o4 = blockIdx.x * 256 + threadIdx.x;  // 65536 float4s
  const int kq = o4 & 31, jj = (o4 >> 5) & 31, kc = (o4 >> 10) & 3, ejb = o4 >> 12;
  const int row = ejb * 32 + jj;
  ((float4*)WP)[o4] = ((const float4*)W)[(size_t)row * 128 + kc * 32 + kq];
}

__global__ void k_init_nxt(float* __restrict__ nxt) {
  nxt[threadIdx.x] = -1.0f;  // SOS
}

// ---------------- persistent-kernel building blocks ----------------
// One wave: out[b=lane][j0..j0+32) partial over k-chunk kc.
// h per-lane in VGPRs; weights wave-uniform (s_load path). Partials -> LDS.
__device__ __forceinline__ void gemm_wave(const float* __restrict__ hsrc, int b,
                                          const float* __restrict__ wbase,
                                          float* pLDS, int kc, int lane) {
  float4 hreg[32];
  const float4* hp = (const float4*)(hsrc + (size_t)b * NH + kc * 128);
#pragma unroll
  for (int kq = 0; kq < 32; ++kq) hreg[kq] = hp[kq];
#pragma unroll 2
  for (int jj = 0; jj < 32; ++jj) {
    const float4* wr = (const float4*)(wbase + jj * 128);
    float a0 = 0.f, a1 = 0.f, a2 = 0.f, a3 = 0.f;
#pragma unroll
    for (int kq = 0; kq < 32; ++kq) {
      const float4 wq = wr[kq];
      const float4 hq = hreg[kq];
      a0 = fmaf(hq.x, wq.x, a0);
      a1 = fmaf(hq.y, wq.y, a1);
      a2 = fmaf(hq.z, wq.z, a2);
      a3 = fmaf(hq.w, wq.w, a3);
    }
    pLDS[(kc * 32 + jj) * 64 + lane] = (a0 + a1) + (a2 + a3);
  }
}

__device__ __forceinline__ void lstm_phase(const float* pLDS, float* cL,
                                           const float* __restrict__ A,
                                           const float* __restrict__ D,
                                           const float* __restrict__ xptr, int xstride,
                                           float* __restrict__ hdst, int b0, int u0,
                                           int tid) {
#pragma unroll
  for (int e = 0; e < 2; ++e) {
    const int cell = tid + e * 256;
    const int uu = cell >> 6, bb = cell & 63;
    const float x = xptr[(size_t)bb * xstride];
    float g4[4];
#pragma unroll
    for (int g = 0; g < 4; ++g) {
      const int jj = uu * 4 + g;
      const int r = g * 512 + u0 + uu;
      float s = fmaf(x, A[r], D[r]);
      s += pLDS[(0 * 32 + jj) * 64 + bb];
      s += pLDS[(1 * 32 + jj) * 64 + bb];
      s += pLDS[(2 * 32 + jj) * 64 + bb];
      s += pLDS[(3 * 32 + jj) * 64 + bb];
      g4[g] = s;
    }
    const float gi = fast_sigmoid(g4[0]);
    const float gf = fast_sigmoid(g4[1]);
    const float gg = fast_tanh(g4[2]);
    const float go = fast_sigmoid(g4[3]);
    const float cn = gf * cL[cell] + gi * gg;
    cL[cell] = cn;
    hdst[(size_t)(b0 + bb) * NH + (u0 + uu)] = go * fast_tanh(cn);
  }
}

__device__ __forceinline__ void proj_reduce_store(const float* pLDS,
                                                  const float* __restrict__ bias,
                                                  float* __restrict__ dst,
                                                  size_t dst_b_stride, int b0, int j0,
                                                  int tid) {
#pragma unroll
  for (int e = 0; e < 8; ++e) {
    const int cell = tid + e * 256;
    const int jj = cell >> 6, bb = cell & 63;
    float s = pLDS[(0 * 32 + jj) * 64 + bb] + pLDS[(1 * 32 + jj) * 64 + bb];
    s += pLDS[(2 * 32 + jj) * 64 + bb];
    s += pLDS[(3 * 32 + jj) * 64 + bb];
    dst[(size_t)(b0 + bb) * dst_b_stride + (j0 + jj)] = s + bias[j0 + jj];
  }
}

// ---------------- encoder: 256 persistent steps ----------------
__global__ __launch_bounds__(256, 3) void k_encoder(
    const float* __restrict__ in_seq, const float* __restrict__ WGP,
    const float* __restrict__ W1P, const float* __restrict__ A,
    const float* __restrict__ D, const float* __restrict__ w1b,
    float* __restrict__ buf0, float* __restrict__ buf1, float* __restrict__ ep,
    float* __restrict__ cbuf, unsigned* __restrict__ bar) {
  __shared__ float pLDS[8192];
  __shared__ float cL[512];
  const int bid = blockIdx.x, tid = threadIdx.x, lane = tid & 63;
  const int kc = __builtin_amdgcn_readfirstlane(tid >> 6);
  const bool ismain = bid < 512;
  if (ismain) { cL[tid] = 0.f; cL[tid + 256] = 0.f; }
  for (int s = 0; s < NL; ++s) {
    const float* hsrc = (s & 1) ? buf0 : buf1;  // buf[(s+1)&1] = h_{s-1}
    float* hdst = (s & 1) ? buf1 : buf0;        // buf[s&1]     = h_s
    if (ismain) {
      const int bg = bid >> 6, jb = bid & 63, b0 = bg * 64, u0 = jb * 8;
      gemm_wave(hsrc, b0 + lane, WGP + (size_t)((jb * 4 + kc) * 32) * 128, pLDS, kc, lane);
      __syncthreads();
      lstm_phase(pLDS, cL, A, D, in_seq + (size_t)b0 * NL + s, NL, hdst, b0, u0, tid);
    } else if (s >= 1) {  // ep[s-1] from h_{s-1}
      const int pid = bid - 512, bg = pid >> 4, ejb = pid & 15, b0 = bg * 64, j0 = ejb * 32;
      gemm_wave(hsrc, b0 + lane, W1P + (size_t)((ejb * 4 + kc) * 32) * 128, pLDS, kc, lane);
      __syncthreads();
      proj_reduce_store(pLDS, w1b, ep + (size_t)(s - 1) * NH, (size_t)NL * NH, b0, j0, tid);
    }
    gridbar(bar);
  }
  if (!ismain) {  // ep[255] from h_255 (in buf1)
    const int pid = bid - 512, bg = pid >> 4, ejb = pid & 15, b0 = bg * 64, j0 = ejb * 32;
    gemm_wave(buf1, b0 + lane, W1P + (size_t)((ejb * 4 + kc) * 32) * 128, pLDS, kc, lane);
    __syncthreads();
    proj_reduce_store(pLDS, w1b, ep + (size_t)255 * NH, (size_t)NL * NH, b0, j0, tid);
  } else {  // c handoff
    cbuf[(size_t)bid * 512 + tid] = cL[tid];
    cbuf[(size_t)bid * 512 + tid + 256] = cL[tid + 256];
  }
}

// ---------------- decoder: 256 persistent steps, 3 phases each ----------------
__global__ __launch_bounds__(256, 3) void k_decoder(
    const float* __restrict__ in_seq, const float* __restrict__ WGP,
    const float* __restrict__ W2P, const float* __restrict__ A,
    const float* __restrict__ D, const float* __restrict__ w2b,
    const float* __restrict__ ep, const float* __restrict__ vW,
    const float* __restrict__ vb, float* __restrict__ buf0, float* __restrict__ buf1,
    float* __restrict__ qbuf, float* __restrict__ nxt, float* __restrict__ cbuf,
    float* __restrict__ out_attn, float* __restrict__ out_ptr,
    unsigned* __restrict__ bar) {
  __shared__ float pLDS[8192];
  __shared__ float cL[512];
  __shared__ float ush[256];
  __shared__ float red[2];
  __shared__ int pidx;
  const int bid = blockIdx.x, tid = threadIdx.x, lane = tid & 63;
  const int kc = __builtin_amdgcn_readfirstlane(tid >> 6);
  const int wv = tid >> 6;
  const bool ismain = bid < 512;
  if (ismain) {
    cL[tid] = cbuf[(size_t)bid * 512 + tid];
    cL[tid + 256] = cbuf[(size_t)bid * 512 + tid + 256];
  }
  for (int s = 0; s < NL; ++s) {
    const float* hsrc = (s & 1) ? buf0 : buf1;
    float* hdst = (s & 1) ? buf1 : buf0;
    // P1: gate GEMM + LSTM (x = nxt from previous step's argmax)
    if (ismain) {
      const int bg = bid >> 6, jb = bid & 63, b0 = bg * 64, u0 = jb * 8;
      gemm_wave(hsrc, b0 + lane, WGP + (size_t)((jb * 4 + kc) * 32) * 128, pLDS, kc, lane);
      __syncthreads();
      lstm_phase(pLDS, cL, A, D, nxt + bg * 64, 1, hdst, b0, u0, tid);
    }
    gridbar(bar);
    // P2: q = h_t @ W2^T + b2
    if (!ismain) {
      const int pid = bid - 512, bg = pid >> 4, ejb = pid & 15, b0 = bg * 64, j0 = ejb * 32;
      gemm_wave(hdst, b0 + lane, W2P + (size_t)((ejb * 4 + kc) * 32) * 128, pLDS, kc, lane);
      __syncthreads();
      proj_reduce_store(pLDS, w2b, qbuf, NH, b0, j0, tid);
    }
    gridbar(bar);
    // P3: attention + log_softmax + argmax + feedback, block b = bid
    if (ismain) {
      const int b = bid;
      const float4* q4 = (const float4*)(qbuf + (size_t)b * NH);
      const float4 q0 = q4[lane], q1 = q4[64 + lane];
      const float4* vW4 = (const float4*)vW;
      const float4 v0 = vW4[lane], v1 = vW4[64 + lane];
      const float vbs = vb[0];
      for (int li = 0; li < 64; ++li) {
        const int l = wv * 64 + li;
        const float4* eprow = (const float4*)(ep + ((size_t)b * NL + l) * NH);
        const float4 e0 = eprow[lane], e1 = eprow[64 + lane];
        float sc = v0.x * fast_tanh(e0.x + q0.x);
        sc = fmaf(v0.y, fast_tanh(e0.y + q0.y), sc);
        sc = fmaf(v0.z, fast_tanh(e0.z + q0.z), sc);
        sc = fmaf(v0.w, fast_tanh(e0.w + q0.w), sc);
        sc = fmaf(v1.x, fast_tanh(e1.x + q1.x), sc);
        sc = fmaf(v1.y, fast_tanh(e1.y + q1.y), sc);
        sc = fmaf(v1.z, fast_tanh(e1.z + q1.z), sc);
        sc = fmaf(v1.w, fast_tanh(e1.w + q1.w), sc);
#pragma unroll
        for (int d = 1; d < 64; d <<= 1) sc += __shfl_xor(sc, d, 64);
        if (lane == 0) ush[l] = sc + vbs;
      }
      __syncthreads();
      if (wv == 0) {
        float m = -3.4e38f; int idx = 0;
#pragma unroll
        for (int r = 0; r < 4; ++r) {  // ascending l within lane
          const int l = lane * 4 + r;
          const float uu = ush[l];
          if (uu > m) { m = uu; idx = l; }
        }
#pragma unroll
        for (int d = 1; d < 64; d <<= 1) {  // tie -> smaller index
          const float om = __shfl_xor(m, d, 64);
          const int oi = __shfl_xor(idx, d, 64);
          if (om > m || (om == m && oi < idx)) { m = om; idx = oi; }
        }
        float se = 0.f;
#pragma unroll
        for (int r = 0; r < 4; ++r) se += __expf(ush[lane * 4 + r] - m);
#pragma unroll
        for (int d = 1; d < 64; d <<= 1) se += __shfl_xor(se, d, 64);
        if (lane == 0) { red[0] = m; red[1] = logf(se); pidx = idx; }
      }
      __syncthreads();
      if (tid == 0) {
        out_ptr[(size_t)b * NL + s] = (float)pidx;
        nxt[b] = in_seq[(size_t)b * NL + pidx];  // F=1
      }
      out_attn[((size_t)b * NL + s) * NL + tid] = ush[tid] - red[0] - red[1];
    }
    gridbar(bar);
  }
}

extern "C" void kernel_launch(void* const* d_in, const int* in_sizes, int n_in,
                              void* d_out, int out_size, void* d_ws, size_t ws_size,
                              hipStream_t stream) {
  const float* in_seq   = (const float*)d_in[0];
  const float* enc_embW = (const float*)d_in[1];
  const float* enc_embB = (const float*)d_in[2];
  const float* enc_Wih  = (const float*)d_in[3];
  const float* enc_Whh  = (const float*)d_in[4];
  const float* enc_bih  = (const float*)d_in[5];
  const float* enc_bhh  = (const float*)d_in[6];
  const float* dec_embW = (const float*)d_in[7];
  const float* dec_embB = (const float*)d_in[8];
  const float* dec_Wih  = (const float*)d_in[9];
  const float* dec_Whh  = (const float*)d_in[10];
  const float* dec_bih  = (const float*)d_in[11];
  const float* dec_bhh  = (const float*)d_in[12];
  const float* W1_W     = (const float*)d_in[13];
  const float* W1_b     = (const float*)d_in[14];
  const float* W2_W     = (const float*)d_in[15];
  const float* W2_b     = (const float*)d_in[16];
  const float* v_W      = (const float*)d_in[17];
  const float* v_b      = (const float*)d_in[18];

  float* wsf = (float*)d_ws;
  float* out_attn = (float*)d_out;
  float* out_ptr  = out_attn + (size_t)NB * NL * NL;

  // ---- prep ----
  hipMemsetAsync(wsf + BUF1, 0, (size_t)NB * NH * 4, stream);     // h_{-1} = 0
  hipMemsetAsync(wsf + BAR_OFF, 0, 2048, stream);                 // barrier state
  k_init_nxt<<<1, NB, 0, stream>>>(wsf + NXT_OFF);

  k_perm_gate<<<1024, 256, 0, stream>>>(enc_Whh, wsf + WGP_ENC);
  k_perm_gate<<<1024, 256, 0, stream>>>(dec_Whh, wsf + WGP_DEC);
  k_perm_proj<<<256, 256, 0, stream>>>(W1_W, wsf + W1P_OFF);
  k_perm_proj<<<256, 256, 0, stream>>>(W2_W, wsf + W2P_OFF);

  k_prep_ad<<<512, 256, 0, stream>>>(enc_Wih, enc_embW, enc_embB, enc_bih, enc_bhh,
                                     wsf + A_ENC, wsf + D_ENC);
  k_prep_ad<<<512, 256, 0, stream>>>(dec_Wih, dec_embW, dec_embB, dec_bih, dec_bhh,
                                     wsf + A_DEC, wsf + D_DEC);

  // ---- persistent encoder + decoder ----
  k_encoder<<<NBLK, 256, 0, stream>>>(in_seq, wsf + WGP_ENC, wsf + W1P_OFF, wsf + A_ENC,
                                      wsf + D_ENC, W1_b, wsf + BUF0, wsf + BUF1,
                                      wsf + EP_OFF, wsf + CBUF,
                                      (unsigned*)(wsf + BAR_OFF));
  k_decoder<<<NBLK, 256, 0, stream>>>(in_seq, wsf + WGP_DEC, wsf + W2P_OFF, wsf + A_DEC,
                                      wsf + D_DEC, W2_b, wsf + EP_OFF, v_W, v_b,
                                      wsf + BUF0, wsf + BUF1, wsf + QBUF, wsf + NXT_OFF,
                                      wsf + CBUF, out_attn, out_ptr,
                                      (unsigned*)(wsf + BAR_OFF));
}

// Round 5
// 129975.769 us; speedup vs baseline: 2.2895x; 2.2895x over previous
//
#include <hip/hip_runtime.h>
#include <math.h>

#define NB 512   // batch
#define NL 256   // seq len
#define NH 512   // hidden
#define NG 2048  // 4*H
#define NBLK 640 // persistent grid: 512 main + 128 proj

// ---------------- ws layout (float offsets) ----------------
#define WGP_ENC  ((size_t)0)          // 1,048,576  permuted gate weights [jb][kc][jj][kk]
#define WGP_DEC  ((size_t)1048576)    // 1,048,576
#define W1P_OFF  ((size_t)2097152)    // 262,144    permuted W1 [ejb][kc][jj][kk]
#define W2P_OFF  ((size_t)2359296)    // 262,144
#define A_ENC    ((size_t)2621440)    // 2048
#define D_ENC    ((size_t)2623488)    // 2048
#define A_DEC    ((size_t)2625536)    // 2048
#define D_DEC    ((size_t)2627584)    // 2048
#define BUF0     ((size_t)2629632)    // 262,144  h ping  [b][k]
#define BUF1     ((size_t)2891776)    // 262,144  h pong
#define CBUF     ((size_t)3153920)    // 262,144  c handoff enc->dec
#define QBUF     ((size_t)3416064)    // 262,144  q [b][h]
#define NXT_OFF  ((size_t)3678208)    // 512
#define BAR_OFF  ((size_t)3678720)    // 512 floats reserved (barrier counters)
#define EP_OFF   ((size_t)3679232)    // 256*512*512  enc_proj [b][l][h]
// total = 70,788,096 floats = 283.2 MB

__device__ __forceinline__ float fast_rcp(float x) {
  return __builtin_amdgcn_rcpf(x);
}
__device__ __forceinline__ float fast_tanh(float x) {
  x = fminf(x, 10.0f);
  float t = __expf(2.0f * x);
  return 1.0f - 2.0f * fast_rcp(t + 1.0f);
}
__device__ __forceinline__ float fast_sigmoid(float x) {
  return fast_rcp(1.0f + __expf(-x));
}

// ---------------- 2-level grid barrier (640 blocks) ----------------
__device__ __forceinline__ void gridbar(unsigned* bar) {
  __syncthreads();
  if (threadIdx.x == 0) {
    __threadfence();  // release
    unsigned* gen = bar + 288;
    const unsigned g = __hip_atomic_load(gen, __ATOMIC_RELAXED, __HIP_MEMORY_SCOPE_AGENT);
    const int leaf = blockIdx.x & 7;
    unsigned a = __hip_atomic_fetch_add(bar + leaf * 32, 1u, __ATOMIC_ACQ_REL,
                                        __HIP_MEMORY_SCOPE_AGENT);
    if (a == (NBLK / 8) - 1) {
      unsigned r = __hip_atomic_fetch_add(bar + 256, 1u, __ATOMIC_ACQ_REL,
                                          __HIP_MEMORY_SCOPE_AGENT);
      if (r == 7) {
#pragma unroll
        for (int i = 0; i < 8; ++i)
          __hip_atomic_store(bar + i * 32, 0u, __ATOMIC_RELAXED, __HIP_MEMORY_SCOPE_AGENT);
        __hip_atomic_store(bar + 256, 0u, __ATOMIC_RELAXED, __HIP_MEMORY_SCOPE_AGENT);
        __hip_atomic_store(gen, g + 1u, __ATOMIC_RELEASE, __HIP_MEMORY_SCOPE_AGENT);
      } else {
        while (__hip_atomic_load(gen, __ATOMIC_RELAXED, __HIP_MEMORY_SCOPE_AGENT) == g)
          __builtin_amdgcn_s_sleep(1);
      }
    } else {
      while (__hip_atomic_load(gen, __ATOMIC_RELAXED, __HIP_MEMORY_SCOPE_AGENT) == g)
        __builtin_amdgcn_s_sleep(1);
    }
    __threadfence();  // acquire
  }
  __syncthreads();
}

// ---------------- prep kernels ----------------
__global__ void k_prep_ad(const float* __restrict__ Wih, const float* __restrict__ embW,
                          const float* __restrict__ embB, const float* __restrict__ bih,
                          const float* __restrict__ bhh, float* __restrict__ A,
                          float* __restrict__ D) {
  const int wv = threadIdx.x >> 6, lane = threadIdx.x & 63;
  const int j = blockIdx.x * 4 + wv;
  const float* __restrict__ row = Wih + (size_t)j * NH;
  float a = 0.f, d = 0.f;
#pragma unroll
  for (int r = 0; r < 8; ++r) {
    const int k = lane + 64 * r;
    const float w = row[k];
    a = fmaf(w, embW[k], a);
    d = fmaf(w, embB[k], d);
  }
#pragma unroll
  for (int dd = 1; dd < 64; dd <<= 1) {
    a += __shfl_xor(a, dd, 64);
    d += __shfl_xor(d, dd, 64);
  }
  if (lane == 0) { A[j] = a; D[j] = d + bih[j] + bhh[j]; }
}

// WGP[jb][kc][jj][kk] = Whh[(jj&3)*512 + jb*8 + (jj>>2)][kc*128+kk]
__global__ void k_perm_gate(const float* __restrict__ Whh, float* __restrict__ WGP) {
  const int o4 = blockIdx.x * 256 + threadIdx.x;  // 262144 float4s
  const int kq = o4 & 31, jj = (o4 >> 5) & 31, kc = (o4 >> 10) & 3, jb = o4 >> 12;
  const int r = (jj & 3) * 512 + jb * 8 + (jj >> 2);
  ((float4*)WGP)[o4] = ((const float4*)Whh)[(size_t)r * 128 + kc * 32 + kq];
}

// WP[ejb][kc][jj][kk] = W[ejb*32+jj][kc*128+kk]
__global__ void k_perm_proj(const float* __restrict__ W, float* __restrict__ WP) {
  const int o4 = blockIdx.x * 256 + threadIdx.x;  // 65536 float4s
  const int kq = o4 & 31, jj = (o4 >> 5) & 31, kc = (o4 >> 10) & 3, ejb = o4 >> 12;
  const int row = ejb * 32 + jj;
  ((float4*)WP)[o4] = ((const float4*)W)[(size_t)row * 128 + kc * 32 + kq];
}

__global__ void k_init_nxt(float* __restrict__ nxt) {
  nxt[threadIdx.x] = -1.0f;  // SOS
}

// ---------------- persistent-kernel building blocks ----------------
// One wave: out[b=lane][j0..j0+32) partial over k-chunk kc.
// Register-bounded: acc[32] scalars + h in 4 sub-chunks of 8 float4 (32 VGPR live).
// Peak pressure ~110 VGPR < 170 cap @ 3 waves/EU -> no scratch spill (round-4 lesson:
// hreg[32] float4 = 128 VGPR spilled at VGPR_Count=84, causing 600 MB/step scratch).
__device__ __forceinline__ void gemm_wave(const float* __restrict__ hsrc, int b,
                                          const float* __restrict__ wbase,
                                          float* pLDS, int kc, int lane) {
  float acc[32];
#pragma unroll
  for (int jj = 0; jj < 32; ++jj) acc[jj] = 0.f;
  const float4* hp = (const float4*)(hsrc + (size_t)b * NH + kc * 128);
#pragma unroll
  for (int sub = 0; sub < 4; ++sub) {
    float4 h4[8];
#pragma unroll
    for (int q = 0; q < 8; ++q) h4[q] = hp[sub * 8 + q];
#pragma unroll
    for (int jj = 0; jj < 32; ++jj) {
      const float4* wr = (const float4*)(wbase + jj * 128) + sub * 8;
      float a0 = 0.f, a1 = 0.f, a2 = 0.f, a3 = 0.f;
#pragma unroll
      for (int q = 0; q < 8; ++q) {
        const float4 wq = wr[q];
        a0 = fmaf(h4[q].x, wq.x, a0);
        a1 = fmaf(h4[q].y, wq.y, a1);
        a2 = fmaf(h4[q].z, wq.z, a2);
        a3 = fmaf(h4[q].w, wq.w, a3);
      }
      acc[jj] += (a0 + a1) + (a2 + a3);
    }
  }
#pragma unroll
  for (int jj = 0; jj < 32; ++jj)
    pLDS[(kc * 32 + jj) * 64 + lane] = acc[jj];
}

__device__ __forceinline__ void lstm_phase(const float* pLDS, float* cL,
                                           const float* __restrict__ A,
                                           const float* __restrict__ D,
                                           const float* __restrict__ xptr, int xstride,
                                           float* __restrict__ hdst, int b0, int u0,
                                           int tid) {
#pragma unroll
  for (int e = 0; e < 2; ++e) {
    const int cell = tid + e * 256;
    const int uu = cell >> 6, bb = cell & 63;
    const float x = xptr[(size_t)bb * xstride];
    float g4[4];
#pragma unroll
    for (int g = 0; g < 4; ++g) {
      const int jj = uu * 4 + g;
      const int r = g * 512 + u0 + uu;
      float s = fmaf(x, A[r], D[r]);
      s += pLDS[(0 * 32 + jj) * 64 + bb];
      s += pLDS[(1 * 32 + jj) * 64 + bb];
      s += pLDS[(2 * 32 + jj) * 64 + bb];
      s += pLDS[(3 * 32 + jj) * 64 + bb];
      g4[g] = s;
    }
    const float gi = fast_sigmoid(g4[0]);
    const float gf = fast_sigmoid(g4[1]);
    const float gg = fast_tanh(g4[2]);
    const float go = fast_sigmoid(g4[3]);
    const float cn = gf * cL[cell] + gi * gg;
    cL[cell] = cn;
    hdst[(size_t)(b0 + bb) * NH + (u0 + uu)] = go * fast_tanh(cn);
  }
}

__device__ __forceinline__ void proj_reduce_store(const float* pLDS,
                                                  const float* __restrict__ bias,
                                                  float* __restrict__ dst,
                                                  size_t dst_b_stride, int b0, int j0,
                                                  int tid) {
#pragma unroll
  for (int e = 0; e < 8; ++e) {
    const int cell = tid + e * 256;
    const int jj = cell >> 6, bb = cell & 63;
    float s = pLDS[(0 * 32 + jj) * 64 + bb] + pLDS[(1 * 32 + jj) * 64 + bb];
    s += pLDS[(2 * 32 + jj) * 64 + bb];
    s += pLDS[(3 * 32 + jj) * 64 + bb];
    dst[(size_t)(b0 + bb) * dst_b_stride + (j0 + jj)] = s + bias[j0 + jj];
  }
}

// ---------------- encoder: 256 persistent steps ----------------
__global__ __launch_bounds__(256, 3) void k_encoder(
    const float* __restrict__ in_seq, const float* __restrict__ WGP,
    const float* __restrict__ W1P, const float* __restrict__ A,
    const float* __restrict__ D, const float* __restrict__ w1b,
    float* __restrict__ buf0, float* __restrict__ buf1, float* __restrict__ ep,
    float* __restrict__ cbuf, unsigned* __restrict__ bar) {
  __shared__ float pLDS[8192];
  __shared__ float cL[512];
  const int bid = blockIdx.x, tid = threadIdx.x, lane = tid & 63;
  const int kc = __builtin_amdgcn_readfirstlane(tid >> 6);
  const bool ismain = bid < 512;
  if (ismain) { cL[tid] = 0.f; cL[tid + 256] = 0.f; }
  for (int s = 0; s < NL; ++s) {
    const float* hsrc = (s & 1) ? buf0 : buf1;  // buf[(s+1)&1] = h_{s-1}
    float* hdst = (s & 1) ? buf1 : buf0;        // buf[s&1]     = h_s
    if (ismain) {
      const int bg = bid >> 6, jb = bid & 63, b0 = bg * 64, u0 = jb * 8;
      gemm_wave(hsrc, b0 + lane, WGP + (size_t)((jb * 4 + kc) * 32) * 128, pLDS, kc, lane);
      __syncthreads();
      lstm_phase(pLDS, cL, A, D, in_seq + (size_t)b0 * NL + s, NL, hdst, b0, u0, tid);
    } else if (s >= 1) {  // ep[s-1] from h_{s-1}
      const int pid = bid - 512, bg = pid >> 4, ejb = pid & 15, b0 = bg * 64, j0 = ejb * 32;
      gemm_wave(hsrc, b0 + lane, W1P + (size_t)((ejb * 4 + kc) * 32) * 128, pLDS, kc, lane);
      __syncthreads();
      proj_reduce_store(pLDS, w1b, ep + (size_t)(s - 1) * NH, (size_t)NL * NH, b0, j0, tid);
    }
    gridbar(bar);
  }
  if (!ismain) {  // ep[255] from h_255 (in buf1)
    const int pid = bid - 512, bg = pid >> 4, ejb = pid & 15, b0 = bg * 64, j0 = ejb * 32;
    gemm_wave(buf1, b0 + lane, W1P + (size_t)((ejb * 4 + kc) * 32) * 128, pLDS, kc, lane);
    __syncthreads();
    proj_reduce_store(pLDS, w1b, ep + (size_t)255 * NH, (size_t)NL * NH, b0, j0, tid);
  } else {  // c handoff
    cbuf[(size_t)bid * 512 + tid] = cL[tid];
    cbuf[(size_t)bid * 512 + tid + 256] = cL[tid + 256];
  }
}

// ---------------- decoder: 256 persistent steps, 3 phases each ----------------
__global__ __launch_bounds__(256, 3) void k_decoder(
    const float* __restrict__ in_seq, const float* __restrict__ WGP,
    const float* __restrict__ W2P, const float* __restrict__ A,
    const float* __restrict__ D, const float* __restrict__ w2b,
    const float* __restrict__ ep, const float* __restrict__ vW,
    const float* __restrict__ vb, float* __restrict__ buf0, float* __restrict__ buf1,
    float* __restrict__ qbuf, float* __restrict__ nxt, float* __restrict__ cbuf,
    float* __restrict__ out_attn, float* __restrict__ out_ptr,
    unsigned* __restrict__ bar) {
  __shared__ float pLDS[8192];
  __shared__ float cL[512];
  __shared__ float ush[256];
  __shared__ float red[2];
  __shared__ int pidx;
  const int bid = blockIdx.x, tid = threadIdx.x, lane = tid & 63;
  const int kc = __builtin_amdgcn_readfirstlane(tid >> 6);
  const int wv = tid >> 6;
  const bool ismain = bid < 512;
  if (ismain) {
    cL[tid] = cbuf[(size_t)bid * 512 + tid];
    cL[tid + 256] = cbuf[(size_t)bid * 512 + tid + 256];
  }
  for (int s = 0; s < NL; ++s) {
    const float* hsrc = (s & 1) ? buf0 : buf1;
    float* hdst = (s & 1) ? buf1 : buf0;
    // P1: gate GEMM + LSTM (x = nxt from previous step's argmax)
    if (ismain) {
      const int bg = bid >> 6, jb = bid & 63, b0 = bg * 64, u0 = jb * 8;
      gemm_wave(hsrc, b0 + lane, WGP + (size_t)((jb * 4 + kc) * 32) * 128, pLDS, kc, lane);
      __syncthreads();
      lstm_phase(pLDS, cL, A, D, nxt + bg * 64, 1, hdst, b0, u0, tid);
    }
    gridbar(bar);
    // P2: q = h_t @ W2^T + b2
    if (!ismain) {
      const int pid = bid - 512, bg = pid >> 4, ejb = pid & 15, b0 = bg * 64, j0 = ejb * 32;
      gemm_wave(hdst, b0 + lane, W2P + (size_t)((ejb * 4 + kc) * 32) * 128, pLDS, kc, lane);
      __syncthreads();
      proj_reduce_store(pLDS, w2b, qbuf, NH, b0, j0, tid);
    }
    gridbar(bar);
    // P3: attention + log_softmax + argmax + feedback, block b = bid
    if (ismain) {
      const int b = bid;
      const float4* q4 = (const float4*)(qbuf + (size_t)b * NH);
      const float4 q0 = q4[lane], q1 = q4[64 + lane];
      const float4* vW4 = (const float4*)vW;
      const float4 v0 = vW4[lane], v1 = vW4[64 + lane];
      const float vbs = vb[0];
      // 1-deep software prefetch over the 64 ep rows this wave scans
      const float4* row0 = (const float4*)(ep + ((size_t)b * NL + wv * 64) * NH);
      float4 e0 = row0[lane], e1 = row0[64 + lane];
      for (int li = 0; li < 64; ++li) {
        const int l = wv * 64 + li;
        float4 n0, n1;
        if (li < 63) {
          const float4* nrow = (const float4*)(ep + ((size_t)b * NL + l + 1) * NH);
          n0 = nrow[lane];
          n1 = nrow[64 + lane];
        }
        float sc = v0.x * fast_tanh(e0.x + q0.x);
        sc = fmaf(v0.y, fast_tanh(e0.y + q0.y), sc);
        sc = fmaf(v0.z, fast_tanh(e0.z + q0.z), sc);
        sc = fmaf(v0.w, fast_tanh(e0.w + q0.w), sc);
        sc = fmaf(v1.x, fast_tanh(e1.x + q1.x), sc);
        sc = fmaf(v1.y, fast_tanh(e1.y + q1.y), sc);
        sc = fmaf(v1.z, fast_tanh(e1.z + q1.z), sc);
        sc = fmaf(v1.w, fast_tanh(e1.w + q1.w), sc);
#pragma unroll
        for (int d = 1; d < 64; d <<= 1) sc += __shfl_xor(sc, d, 64);
        if (lane == 0) ush[l] = sc + vbs;
        e0 = n0;
        e1 = n1;
      }
      __syncthreads();
      if (wv == 0) {
        float m = -3.4e38f; int idx = 0;
#pragma unroll
        for (int r = 0; r < 4; ++r) {  // ascending l within lane
          const int l = lane * 4 + r;
          const float uu = ush[l];
          if (uu > m) { m = uu; idx = l; }
        }
#pragma unroll
        for (int d = 1; d < 64; d <<= 1) {  // tie -> smaller index
          const float om = __shfl_xor(m, d, 64);
          const int oi = __shfl_xor(idx, d, 64);
          if (om > m || (om == m && oi < idx)) { m = om; idx = oi; }
        }
        float se = 0.f;
#pragma unroll
        for (int r = 0; r < 4; ++r) se += __expf(ush[lane * 4 + r] - m);
#pragma unroll
        for (int d = 1; d < 64; d <<= 1) se += __shfl_xor(se, d, 64);
        if (lane == 0) { red[0] = m; red[1] = logf(se); pidx = idx; }
      }
      __syncthreads();
      if (tid == 0) {
        out_ptr[(size_t)b * NL + s] = (float)pidx;
        nxt[b] = in_seq[(size_t)b * NL + pidx];  // F=1
      }
      out_attn[((size_t)b * NL + s) * NL + tid] = ush[tid] - red[0] - red[1];
    }
    gridbar(bar);
  }
}

extern "C" void kernel_launch(void* const* d_in, const int* in_sizes, int n_in,
                              void* d_out, int out_size, void* d_ws, size_t ws_size,
                              hipStream_t stream) {
  const float* in_seq   = (const float*)d_in[0];
  const float* enc_embW = (const float*)d_in[1];
  const float* enc_embB = (const float*)d_in[2];
  const float* enc_Wih  = (const float*)d_in[3];
  const float* enc_Whh  = (const float*)d_in[4];
  const float* enc_bih  = (const float*)d_in[5];
  const float* enc_bhh  = (const float*)d_in[6];
  const float* dec_embW = (const float*)d_in[7];
  const float* dec_embB = (const float*)d_in[8];
  const float* dec_Wih  = (const float*)d_in[9];
  const float* dec_Whh  = (const float*)d_in[10];
  const float* dec_bih  = (const float*)d_in[11];
  const float* dec_bhh  = (const float*)d_in[12];
  const float* W1_W     = (const float*)d_in[13];
  const float* W1_b     = (const float*)d_in[14];
  const float* W2_W     = (const float*)d_in[15];
  const float* W2_b     = (const float*)d_in[16];
  const float* v_W      = (const float*)d_in[17];
  const float* v_b      = (const float*)d_in[18];

  float* wsf = (float*)d_ws;
  float* out_attn = (float*)d_out;
  float* out_ptr  = out_attn + (size_t)NB * NL * NL;

  // ---- prep ----
  hipMemsetAsync(wsf + BUF1, 0, (size_t)NB * NH * 4, stream);     // h_{-1} = 0
  hipMemsetAsync(wsf + BAR_OFF, 0, 2048, stream);                 // barrier state
  k_init_nxt<<<1, NB, 0, stream>>>(wsf + NXT_OFF);

  k_perm_gate<<<1024, 256, 0, stream>>>(enc_Whh, wsf + WGP_ENC);
  k_perm_gate<<<1024, 256, 0, stream>>>(dec_Whh, wsf + WGP_DEC);
  k_perm_proj<<<256, 256, 0, stream>>>(W1_W, wsf + W1P_OFF);
  k_perm_proj<<<256, 256, 0, stream>>>(W2_W, wsf + W2P_OFF);

  k_prep_ad<<<512, 256, 0, stream>>>(enc_Wih, enc_embW, enc_embB, enc_bih, enc_bhh,
                                     wsf + A_ENC, wsf + D_ENC);
  k_prep_ad<<<512, 256, 0, stream>>>(dec_Wih, dec_embW, dec_embB, dec_bih, dec_bhh,
                                     wsf + A_DEC, wsf + D_DEC);

  // ---- persistent encoder + decoder ----
  k_encoder<<<NBLK, 256, 0, stream>>>(in_seq, wsf + WGP_ENC, wsf + W1P_OFF, wsf + A_ENC,
                                      wsf + D_ENC, W1_b, wsf + BUF0, wsf + BUF1,
                                      wsf + EP_OFF, wsf + CBUF,
                                      (unsigned*)(wsf + BAR_OFF));
  k_decoder<<<NBLK, 256, 0, stream>>>(in_seq, wsf + WGP_DEC, wsf + W2P_OFF, wsf + A_DEC,
                                      wsf + D_DEC, W2_b, wsf + EP_OFF, v_W, v_b,
                                      wsf + BUF0, wsf + BUF1, wsf + QBUF, wsf + NXT_OFF,
                                      wsf + CBUF, out_attn, out_ptr,
                                      (unsigned*)(wsf + BAR_OFF));
}

// Round 7
// 63832.745 us; speedup vs baseline: 4.6618x; 2.0362x over previous
//
#include <hip/hip_runtime.h>
#include <math.h>

#define NB 512   // batch
#define NL 256   // seq len
#define NH 512   // hidden
#define NG 2048  // 4*H
#define NBLK 640 // persistent grid: 512 main + 128 proj
#define NLEAF 32 // barrier tree leaves

typedef float f4 __attribute__((ext_vector_type(4)));  // clang vector: ok for nontemporal

// ---------------- ws layout (float offsets) ----------------
#define WGP_ENC  ((size_t)0)          // 1,048,576  permuted gate weights [jb][kc][jj][kk]
#define WGP_DEC  ((size_t)1048576)    // 1,048,576
#define W1P_OFF  ((size_t)2097152)    // 262,144    permuted W1 [ejb][kc][jj][kk]
#define W2P_OFF  ((size_t)2359296)    // 262,144
#define A_ENC    ((size_t)2621440)    // 2048
#define D_ENC    ((size_t)2623488)    // 2048
#define A_DEC    ((size_t)2625536)    // 2048
#define D_DEC    ((size_t)2627584)    // 2048
#define BUF0     ((size_t)2629632)    // 262,144  h ping  [u][b]  (TRANSPOSED)
#define BUF1     ((size_t)2891776)    // 262,144  h pong  [u][b]
#define CBUF     ((size_t)3153920)    // 262,144  c handoff enc->dec
#define QBUF     ((size_t)3416064)    // 262,144  q [b][h]
#define NXT_OFF  ((size_t)3678208)    // 512
#define BAR_OFF  ((size_t)3678720)    // 2048 floats (barrier tree)
#define EP_OFF   ((size_t)3680768)    // 256*512*512  enc_proj [b][l][h]
// total = 70,789,632 floats = 283.2 MB

__device__ __forceinline__ float fast_rcp(float x) {
  return __builtin_amdgcn_rcpf(x);
}
__device__ __forceinline__ float fast_tanh(float x) {
  x = fminf(x, 10.0f);
  float t = __expf(2.0f * x);
  return 1.0f - 2.0f * fast_rcp(t + 1.0f);
}
__device__ __forceinline__ float fast_sigmoid(float x) {
  return fast_rcp(1.0f + __expf(-x));
}

// ---- per-word device-coherent access (sc0 sc1 path; no cache-wide fences) ----
__device__ __forceinline__ float aload_f(const float* p) {
  unsigned v = __hip_atomic_load((const unsigned*)p, __ATOMIC_RELAXED,
                                 __HIP_MEMORY_SCOPE_AGENT);
  union { unsigned u; float f; } c; c.u = v; return c.f;
}
__device__ __forceinline__ void astore_f(float* p, float v) {
  union { float f; unsigned u; } c; c.f = v;
  __hip_atomic_store((unsigned*)p, c.u, __ATOMIC_RELAXED, __HIP_MEMORY_SCOPE_AGENT);
}
__device__ __forceinline__ float2 aload_f2(const float* p) {
  unsigned long long v = __hip_atomic_load((const unsigned long long*)p,
                                           __ATOMIC_RELAXED, __HIP_MEMORY_SCOPE_AGENT);
  union { unsigned long long u; float2 f; } c; c.u = v; return c.f;
}

// ---------------- fence-free 2-level grid barrier (640 blocks) ----------------
// Round-5 lesson: ACQ_REL atomics + __threadfence at agent scope emit
// buffer_wbl2/buffer_inv (full L2 walk/invalidate) per block per barrier ->
// ~117 us/barrier and cold L2 every phase. All-relaxed + s_waitcnt ordering
// keeps L2 warm; data crossing blocks uses aload/astore (sc0 sc1) instead.
// bar[i*32] i<32: leaf counters; bar[1024]: root; bar[1056]: generation.
__device__ __forceinline__ void gridbar(unsigned* bar) {
  __syncthreads();  // drains each wave's vmcnt -> block's sc-stores are ACKed
  if (threadIdx.x == 0) {
    asm volatile("" ::: "memory");
    unsigned* gen = bar + 1056;
    const unsigned g = __hip_atomic_load(gen, __ATOMIC_RELAXED, __HIP_MEMORY_SCOPE_AGENT);
    const int leaf = blockIdx.x & (NLEAF - 1);
    unsigned a = __hip_atomic_fetch_add(bar + leaf * 32, 1u, __ATOMIC_RELAXED,
                                        __HIP_MEMORY_SCOPE_AGENT);
    if (a == (NBLK / NLEAF) - 1) {
      unsigned r = __hip_atomic_fetch_add(bar + 1024, 1u, __ATOMIC_RELAXED,
                                          __HIP_MEMORY_SCOPE_AGENT);
      if (r == NLEAF - 1) {
#pragma unroll
        for (int i = 0; i < NLEAF; ++i)
          __hip_atomic_store(bar + i * 32, 0u, __ATOMIC_RELAXED, __HIP_MEMORY_SCOPE_AGENT);
        __hip_atomic_store(bar + 1024, 0u, __ATOMIC_RELAXED, __HIP_MEMORY_SCOPE_AGENT);
        // resets must be globally visible BEFORE gen flips (else lost-arrival race)
        asm volatile("s_waitcnt vmcnt(0)" ::: "memory");
        __hip_atomic_store(gen, g + 1u, __ATOMIC_RELAXED, __HIP_MEMORY_SCOPE_AGENT);
      } else {
        while (__hip_atomic_load(gen, __ATOMIC_RELAXED, __HIP_MEMORY_SCOPE_AGENT) == g)
          __builtin_amdgcn_s_sleep(2);
      }
    } else {
      while (__hip_atomic_load(gen, __ATOMIC_RELAXED, __HIP_MEMORY_SCOPE_AGENT) == g)
        __builtin_amdgcn_s_sleep(2);
    }
    asm volatile("" ::: "memory");
  }
  __syncthreads();
}

// ---------------- prep kernels ----------------
__global__ void k_prep_ad(const float* __restrict__ Wih, const float* __restrict__ embW,
                          const float* __restrict__ embB, const float* __restrict__ bih,
                          const float* __restrict__ bhh, float* __restrict__ A,
                          float* __restrict__ D) {
  const int wv = threadIdx.x >> 6, lane = threadIdx.x & 63;
  const int j = blockIdx.x * 4 + wv;
  const float* __restrict__ row = Wih + (size_t)j * NH;
  float a = 0.f, d = 0.f;
#pragma unroll
  for (int r = 0; r < 8; ++r) {
    const int k = lane + 64 * r;
    const float w = row[k];
    a = fmaf(w, embW[k], a);
    d = fmaf(w, embB[k], d);
  }
#pragma unroll
  for (int dd = 1; dd < 64; dd <<= 1) {
    a += __shfl_xor(a, dd, 64);
    d += __shfl_xor(d, dd, 64);
  }
  if (lane == 0) { A[j] = a; D[j] = d + bih[j] + bhh[j]; }
}

// WGP[jb][kc][jj][kk] = Whh[(jj&3)*512 + jb*8 + (jj>>2)][kc*128+kk]
__global__ void k_perm_gate(const float* __restrict__ Whh, float* __restrict__ WGP) {
  const int o4 = blockIdx.x * 256 + threadIdx.x;  // 262144 float4s
  const int kq = o4 & 31, jj = (o4 >> 5) & 31, kc = (o4 >> 10) & 3, jb = o4 >> 12;
  const int r = (jj & 3) * 512 + jb * 8 + (jj >> 2);
  ((f4*)WGP)[o4] = ((const f4*)Whh)[(size_t)r * 128 + kc * 32 + kq];
}

// WP[ejb][kc][jj][kk] = W[ejb*32+jj][kc*128+kk]
__global__ void k_perm_proj(const float* __restrict__ W, float* __restrict__ WP) {
  const int o4 = blockIdx.x * 256 + threadIdx.x;  // 65536 float4s
  const int kq = o4 & 31, jj = (o4 >> 5) & 31, kc = (o4 >> 10) & 3, ejb = o4 >> 12;
  const int row = ejb * 32 + jj;
  ((f4*)WP)[o4] = ((const f4*)W)[(size_t)row * 128 + kc * 32 + kq];
}

__global__ void k_init_nxt(float* __restrict__ nxt) {
  nxt[threadIdx.x] = -1.0f;  // SOS
}

// ---------------- persistent-kernel building blocks ----------------
// h layout [u][NB] (transposed): sc-loads are lane-coalesced scalars.
// Sum order identical to round 5: a0..a3 by k mod 4 within each 32-k sub-chunk.
__device__ __forceinline__ void gemm_wave(const float* hsrc, int b0,
                                          const float* wbase, float* pLDS, int kc,
                                          int lane) {
  float acc[32];
#pragma unroll
  for (int jj = 0; jj < 32; ++jj) acc[jj] = 0.f;
  const int k0 = kc * 128;
#pragma unroll
  for (int sub = 0; sub < 4; ++sub) {
    float h32[32];
#pragma unroll
    for (int q = 0; q < 32; ++q)
      h32[q] = aload_f(hsrc + (size_t)(k0 + sub * 32 + q) * NB + b0 + lane);
#pragma unroll
    for (int jj = 0; jj < 32; ++jj) {
      const f4* wr = (const f4*)(wbase + jj * 128 + sub * 32);
      float a0 = 0.f, a1 = 0.f, a2 = 0.f, a3 = 0.f;
#pragma unroll
      for (int q8 = 0; q8 < 8; ++q8) {
        const f4 wq = wr[q8];
        a0 = fmaf(h32[q8 * 4 + 0], wq.x, a0);
        a1 = fmaf(h32[q8 * 4 + 1], wq.y, a1);
        a2 = fmaf(h32[q8 * 4 + 2], wq.z, a2);
        a3 = fmaf(h32[q8 * 4 + 3], wq.w, a3);
      }
      acc[jj] += (a0 + a1) + (a2 + a3);
    }
  }
#pragma unroll
  for (int jj = 0; jj < 32; ++jj)
    pLDS[(kc * 32 + jj) * 64 + lane] = acc[jj];
}

__device__ __forceinline__ void lstm_phase(const float* pLDS, float* cL,
                                           const float* __restrict__ A,
                                           const float* __restrict__ D,
                                           const float* xptr, int xstride,
                                           float* hdst, int b0, int u0, int tid) {
#pragma unroll
  for (int e = 0; e < 2; ++e) {
    const int cell = tid + e * 256;
    const int uu = cell >> 6, bb = cell & 63;
    const float x = aload_f(xptr + (size_t)bb * xstride);
    float g4[4];
#pragma unroll
    for (int g = 0; g < 4; ++g) {
      const int jj = uu * 4 + g;
      const int r = g * 512 + u0 + uu;
      float s = fmaf(x, A[r], D[r]);
      s += pLDS[(0 * 32 + jj) * 64 + bb];
      s += pLDS[(1 * 32 + jj) * 64 + bb];
      s += pLDS[(2 * 32 + jj) * 64 + bb];
      s += pLDS[(3 * 32 + jj) * 64 + bb];
      g4[g] = s;
    }
    const float gi = fast_sigmoid(g4[0]);
    const float gf = fast_sigmoid(g4[1]);
    const float gg = fast_tanh(g4[2]);
    const float go = fast_sigmoid(g4[3]);
    const float cn = gf * cL[cell] + gi * gg;
    cL[cell] = cn;
    // transposed h: [u][b], coalesced across bb
    astore_f(hdst + (size_t)(u0 + uu) * NB + b0 + bb, go * fast_tanh(cn));
  }
}

// dst[b][j] (+bias): qbuf ([b][NH]) or ep slice ([b][NL][NH] at column t)
__device__ __forceinline__ void proj_reduce_store(const float* pLDS,
                                                  const float* __restrict__ bias,
                                                  float* dst, size_t dst_b_stride,
                                                  int b0, int j0, int tid) {
#pragma unroll
  for (int e = 0; e < 8; ++e) {
    const int cell = tid + e * 256;
    const int jj = cell >> 6, bb = cell & 63;
    float s = pLDS[(0 * 32 + jj) * 64 + bb] + pLDS[(1 * 32 + jj) * 64 + bb];
    s += pLDS[(2 * 32 + jj) * 64 + bb];
    s += pLDS[(3 * 32 + jj) * 64 + bb];
    astore_f(dst + (size_t)(b0 + bb) * dst_b_stride + (j0 + jj), s + bias[j0 + jj]);
  }
}

// ---------------- encoder: 256 persistent steps ----------------
__global__ __launch_bounds__(256, 3) void k_encoder(
    const float* __restrict__ in_seq, const float* __restrict__ WGP,
    const float* __restrict__ W1P, const float* __restrict__ A,
    const float* __restrict__ D, const float* __restrict__ w1b,
    float* buf0, float* buf1, float* ep, float* cbuf, unsigned* bar) {
  __shared__ float pLDS[8192];
  __shared__ float cL[512];
  const int bid = blockIdx.x, tid = threadIdx.x, lane = tid & 63;
  const int kc = __builtin_amdgcn_readfirstlane(tid >> 6);
  const bool ismain = bid < 512;
  if (ismain) { cL[tid] = 0.f; cL[tid + 256] = 0.f; }
  for (int s = 0; s < NL; ++s) {
    const float* hsrc = (s & 1) ? buf0 : buf1;  // h_{s-1}
    float* hdst = (s & 1) ? buf1 : buf0;        // h_s
    if (ismain) {
      const int bg = bid >> 6, jb = bid & 63, b0 = bg * 64, u0 = jb * 8;
      gemm_wave(hsrc, b0, WGP + (size_t)((jb * 4 + kc) * 32) * 128, pLDS, kc, lane);
      __syncthreads();
      lstm_phase(pLDS, cL, A, D, in_seq + (size_t)b0 * NL + s, NL, hdst, b0, u0, tid);
    } else if (s >= 1) {  // ep[s-1] from h_{s-1}
      const int pid = bid - 512, bg = pid >> 4, ejb = pid & 15, b0 = bg * 64, j0 = ejb * 32;
      gemm_wave(hsrc, b0, W1P + (size_t)((ejb * 4 + kc) * 32) * 128, pLDS, kc, lane);
      __syncthreads();
      proj_reduce_store(pLDS, w1b, ep + (size_t)(s - 1) * NH, (size_t)NL * NH, b0, j0, tid);
    }
    gridbar(bar);
  }
  if (!ismain) {  // ep[255] from h_255 (in buf1)
    const int pid = bid - 512, bg = pid >> 4, ejb = pid & 15, b0 = bg * 64, j0 = ejb * 32;
    gemm_wave(buf1, b0, W1P + (size_t)((ejb * 4 + kc) * 32) * 128, pLDS, kc, lane);
    __syncthreads();
    proj_reduce_store(pLDS, w1b, ep + (size_t)255 * NH, (size_t)NL * NH, b0, j0, tid);
  } else {  // c handoff (cross-kernel: plain stores, dispatch-end fence covers it)
    cbuf[(size_t)bid * 512 + tid] = cL[tid];
    cbuf[(size_t)bid * 512 + tid + 256] = cL[tid + 256];
  }
}

// ---------------- decoder: 256 persistent steps, 3 phases each ----------------
__global__ __launch_bounds__(256, 3) void k_decoder(
    const float* __restrict__ in_seq, const float* __restrict__ WGP,
    const float* __restrict__ W2P, const float* __restrict__ A,
    const float* __restrict__ D, const float* __restrict__ w2b,
    const float* __restrict__ ep, const float* __restrict__ vW,
    const float* __restrict__ vb, float* buf0, float* buf1, float* qbuf,
    float* nxt, float* cbuf, float* __restrict__ out_attn,
    float* __restrict__ out_ptr, unsigned* bar) {
  __shared__ float pLDS[8192];
  __shared__ float cL[512];
  __shared__ float ush[256];
  __shared__ float red[2];
  __shared__ int pidx;
  const int bid = blockIdx.x, tid = threadIdx.x, lane = tid & 63;
  const int kc = __builtin_amdgcn_readfirstlane(tid >> 6);
  const int wv = tid >> 6;
  const bool ismain = bid < 512;
  if (ismain) {
    cL[tid] = cbuf[(size_t)bid * 512 + tid];
    cL[tid + 256] = cbuf[(size_t)bid * 512 + tid + 256];
  }
  for (int s = 0; s < NL; ++s) {
    const float* hsrc = (s & 1) ? buf0 : buf1;
    float* hdst = (s & 1) ? buf1 : buf0;
    // P1: gate GEMM + LSTM (x = nxt from previous step's argmax)
    if (ismain) {
      const int bg = bid >> 6, jb = bid & 63, b0 = bg * 64, u0 = jb * 8;
      gemm_wave(hsrc, b0, WGP + (size_t)((jb * 4 + kc) * 32) * 128, pLDS, kc, lane);
      __syncthreads();
      lstm_phase(pLDS, cL, A, D, nxt + bg * 64, 1, hdst, b0, u0, tid);
    }
    gridbar(bar);
    // P2: q = h_t @ W2^T + b2
    if (!ismain) {
      const int pid = bid - 512, bg = pid >> 4, ejb = pid & 15, b0 = bg * 64, j0 = ejb * 32;
      gemm_wave(hdst, b0, W2P + (size_t)((ejb * 4 + kc) * 32) * 128, pLDS, kc, lane);
      __syncthreads();
      proj_reduce_store(pLDS, w2b, qbuf, NH, b0, j0, tid);
    }
    gridbar(bar);
    // P3: attention + log_softmax + argmax + feedback, block b = bid
    if (ismain) {
      const int b = bid;
      const float2 qa0 = aload_f2(qbuf + (size_t)b * NH + 4 * lane);
      const float2 qa1 = aload_f2(qbuf + (size_t)b * NH + 4 * lane + 2);
      const float2 qb0 = aload_f2(qbuf + (size_t)b * NH + 256 + 4 * lane);
      const float2 qb1 = aload_f2(qbuf + (size_t)b * NH + 256 + 4 * lane + 2);
      const f4* vW4 = (const f4*)vW;
      const f4 v0 = vW4[lane], v1 = vW4[64 + lane];
      const float vbs = vb[0];
      // 1-deep prefetch; nt loads keep streaming EP from evicting warm weights in L2
      const f4* row0 = (const f4*)(ep + ((size_t)b * NL + wv * 64) * NH);
      f4 e0 = __builtin_nontemporal_load(row0 + lane);
      f4 e1 = __builtin_nontemporal_load(row0 + 64 + lane);
      for (int li = 0; li < 64; ++li) {
        const int l = wv * 64 + li;
        f4 n0, n1;
        if (li < 63) {
          const f4* nrow = (const f4*)(ep + ((size_t)b * NL + l + 1) * NH);
          n0 = __builtin_nontemporal_load(nrow + lane);
          n1 = __builtin_nontemporal_load(nrow + 64 + lane);
        }
        float sc = v0.x * fast_tanh(e0.x + qa0.x);
        sc = fmaf(v0.y, fast_tanh(e0.y + qa0.y), sc);
        sc = fmaf(v0.z, fast_tanh(e0.z + qa1.x), sc);
        sc = fmaf(v0.w, fast_tanh(e0.w + qa1.y), sc);
        sc = fmaf(v1.x, fast_tanh(e1.x + qb0.x), sc);
        sc = fmaf(v1.y, fast_tanh(e1.y + qb0.y), sc);
        sc = fmaf(v1.z, fast_tanh(e1.z + qb1.x), sc);
        sc = fmaf(v1.w, fast_tanh(e1.w + qb1.y), sc);
#pragma unroll
        for (int d = 1; d < 64; d <<= 1) sc += __shfl_xor(sc, d, 64);
        if (lane == 0) ush[l] = sc + vbs;
        e0 = n0;
        e1 = n1;
      }
      __syncthreads();
      if (wv == 0) {
        float m = -3.4e38f; int idx = 0;
#pragma unroll
        for (int r = 0; r < 4; ++r) {  // ascending l within lane
          const int l = lane * 4 + r;
          const float uu = ush[l];
          if (uu > m) { m = uu; idx = l; }
        }
#pragma unroll
        for (int d = 1; d < 64; d <<= 1) {  // tie -> smaller index
          const float om = __shfl_xor(m, d, 64);
          const int oi = __shfl_xor(idx, d, 64);
          if (om > m || (om == m && oi < idx)) { m = om; idx = oi; }
        }
        float se = 0.f;
#pragma unroll
        for (int r = 0; r < 4; ++r) se += __expf(ush[lane * 4 + r] - m);
#pragma unroll
        for (int d = 1; d < 64; d <<= 1) se += __shfl_xor(se, d, 64);
        if (lane == 0) { red[0] = m; red[1] = logf(se); pidx = idx; }
      }
      __syncthreads();
      if (tid == 0) {
        out_ptr[(size_t)b * NL + s] = (float)pidx;
        astore_f(nxt + b, in_seq[(size_t)b * NL + pidx]);  // F=1
      }
      out_attn[((size_t)b * NL + s) * NL + tid] = ush[tid] - red[0] - red[1];
    }
    gridbar(bar);
  }
}

extern "C" void kernel_launch(void* const* d_in, const int* in_sizes, int n_in,
                              void* d_out, int out_size, void* d_ws, size_t ws_size,
                              hipStream_t stream) {
  const float* in_seq   = (const float*)d_in[0];
  const float* enc_embW = (const float*)d_in[1];
  const float* enc_embB = (const float*)d_in[2];
  const float* enc_Wih  = (const float*)d_in[3];
  const float* enc_Whh  = (const float*)d_in[4];
  const float* enc_bih  = (const float*)d_in[5];
  const float* enc_bhh  = (const float*)d_in[6];
  const float* dec_embW = (const float*)d_in[7];
  const float* dec_embB = (const float*)d_in[8];
  const float* dec_Wih  = (const float*)d_in[9];
  const float* dec_Whh  = (const float*)d_in[10];
  const float* dec_bih  = (const float*)d_in[11];
  const float* dec_bhh  = (const float*)d_in[12];
  const float* W1_W     = (const float*)d_in[13];
  const float* W1_b     = (const float*)d_in[14];
  const float* W2_W     = (const float*)d_in[15];
  const float* W2_b     = (const float*)d_in[16];
  const float* v_W      = (const float*)d_in[17];
  const float* v_b      = (const float*)d_in[18];

  float* wsf = (float*)d_ws;
  float* out_attn = (float*)d_out;
  float* out_ptr  = out_attn + (size_t)NB * NL * NL;

  // ---- prep ----
  (void)hipMemsetAsync(wsf + BUF1, 0, (size_t)NB * NH * 4, stream);  // h_{-1} = 0
  (void)hipMemsetAsync(wsf + BAR_OFF, 0, 8192, stream);              // barrier state
  k_init_nxt<<<1, NB, 0, stream>>>(wsf + NXT_OFF);

  k_perm_gate<<<1024, 256, 0, stream>>>(enc_Whh, wsf + WGP_ENC);
  k_perm_gate<<<1024, 256, 0, stream>>>(dec_Whh, wsf + WGP_DEC);
  k_perm_proj<<<256, 256, 0, stream>>>(W1_W, wsf + W1P_OFF);
  k_perm_proj<<<256, 256, 0, stream>>>(W2_W, wsf + W2P_OFF);

  k_prep_ad<<<512, 256, 0, stream>>>(enc_Wih, enc_embW, enc_embB, enc_bih, enc_bhh,
                                     wsf + A_ENC, wsf + D_ENC);
  k_prep_ad<<<512, 256, 0, stream>>>(dec_Wih, dec_embW, dec_embB, dec_bih, dec_bhh,
                                     wsf + A_DEC, wsf + D_DEC);

  // ---- persistent encoder + decoder ----
  k_encoder<<<NBLK, 256, 0, stream>>>(in_seq, wsf + WGP_ENC, wsf + W1P_OFF, wsf + A_ENC,
                                      wsf + D_ENC, W1_b, wsf + BUF0, wsf + BUF1,
                                      wsf + EP_OFF, wsf + CBUF,
                                      (unsigned*)(wsf + BAR_OFF));
  k_decoder<<<NBLK, 256, 0, stream>>>(in_seq, wsf + WGP_DEC, wsf + W2P_OFF, wsf + A_DEC,
                                      wsf + D_DEC, W2_b, wsf + EP_OFF, v_W, v_b,
                                      wsf + BUF0, wsf + BUF1, wsf + QBUF, wsf + NXT_OFF,
                                      wsf + CBUF, out_attn, out_ptr,
                                      (unsigned*)(wsf + BAR_OFF));
}

// Round 8
// 55476.917 us; speedup vs baseline: 5.3640x; 1.1506x over previous
//
#include <hip/hip_runtime.h>
#include <math.h>

#define NB 512   // batch
#define NL 256   // seq len
#define NH 512   // hidden
#define NG 2048  // 4*H
#define NBLKS 128  // persistent-ish blocks; each owns 4 batch rows; no inter-block comms

typedef float f4 __attribute__((ext_vector_type(4)));

// ---------------- ws layout (float offsets) ----------------
#define WTG_ENC  ((size_t)0)          // 1,048,576  WhhT_enc [k=512][j=2048]
#define WTG_DEC  ((size_t)1048576)    // 1,048,576  WhhT_dec
#define W1T_OFF  ((size_t)2097152)    // 262,144    W1T [k=512][j=512]
#define W2T_OFF  ((size_t)2359296)    // 262,144
#define A_ENC    ((size_t)2621440)    // 2048
#define D_ENC    ((size_t)2623488)    // 2048
#define A_DEC    ((size_t)2625536)    // 2048
#define D_DEC    ((size_t)2627584)    // 2048
#define HC_OFF   ((size_t)2629632)    // 128*4096  h,c handoff enc->dec per block
#define EP_OFF   ((size_t)3153920)    // 256*512*512  enc_proj [b][l][h]
// total = 70,262,784 floats = 281.1 MB (283 MB known-good in rounds 5/7)

__device__ __forceinline__ float fast_rcp(float x) {
  return __builtin_amdgcn_rcpf(x);
}
__device__ __forceinline__ float fast_tanh(float x) {
  x = fminf(x, 10.0f);
  float t = __expf(2.0f * x);
  return 1.0f - 2.0f * fast_rcp(t + 1.0f);
}
__device__ __forceinline__ float fast_sigmoid(float x) {
  return fast_rcp(1.0f + __expf(-x));
}
__device__ __forceinline__ f4 fma4(float s, f4 w, f4 a) {
  a.x = fmaf(s, w.x, a.x);
  a.y = fmaf(s, w.y, a.y);
  a.z = fmaf(s, w.z, a.z);
  a.w = fmaf(s, w.w, a.w);
  return a;
}

// ---------------- prep kernels ----------------
// dst[k][j] = src[j][k]; o = k<<lgJ | j
__global__ void k_transpose(const float* __restrict__ src, float* __restrict__ dst,
                            int lgJ, int lgK) {
  const int o = blockIdx.x * 256 + threadIdx.x;
  const int j = o & ((1 << lgJ) - 1), k = o >> lgJ;
  dst[o] = src[((size_t)j << lgK) + k];
}

// A[j] = Wih[j,:]·embW ; D[j] = Wih[j,:]·embB + bih[j] + bhh[j]
__global__ void k_prep_ad(const float* __restrict__ Wih, const float* __restrict__ embW,
                          const float* __restrict__ embB, const float* __restrict__ bih,
                          const float* __restrict__ bhh, float* __restrict__ A,
                          float* __restrict__ D) {
  const int wv = threadIdx.x >> 6, lane = threadIdx.x & 63;
  const int j = blockIdx.x * 4 + wv;
  const float* __restrict__ row = Wih + (size_t)j * NH;
  float a = 0.f, d = 0.f;
#pragma unroll
  for (int r = 0; r < 8; ++r) {
    const int k = lane + 64 * r;
    const float w = row[k];
    a = fmaf(w, embW[k], a);
    d = fmaf(w, embB[k], d);
  }
#pragma unroll
  for (int dd = 1; dd < 64; dd <<= 1) {
    a += __shfl_xor(a, dd, 64);
    d += __shfl_xor(d, dd, 64);
  }
  if (lane == 0) { A[j] = a; D[j] = d + bih[j] + bhh[j]; }
}

// ---------------- in-block building blocks ----------------
// gates GEMV: thread t owns gate-cols 4t..4t+3; h broadcast from LDS; coalesced f4 weights
__device__ __forceinline__ void gemv_gates(const f4* __restrict__ wg,
                                           const float hL[4][512], float gL[4][2048],
                                           int tid) {
  f4 a0 = {0.f, 0.f, 0.f, 0.f}, a1 = a0, a2 = a0, a3 = a0;
#pragma unroll 2
  for (int k4 = 0; k4 < 128; ++k4) {
    const f4 hv0 = *(const f4*)&hL[0][k4 * 4];
    const f4 hv1 = *(const f4*)&hL[1][k4 * 4];
    const f4 hv2 = *(const f4*)&hL[2][k4 * 4];
    const f4 hv3 = *(const f4*)&hL[3][k4 * 4];
#pragma unroll
    for (int kk = 0; kk < 4; ++kk) {
      const f4 w = wg[(size_t)(k4 * 4 + kk) * 512];
      a0 = fma4(hv0[kk], w, a0);
      a1 = fma4(hv1[kk], w, a1);
      a2 = fma4(hv2[kk], w, a2);
      a3 = fma4(hv3[kk], w, a3);
    }
  }
  *(f4*)&gL[0][4 * tid] = a0;
  *(f4*)&gL[1][4 * tid] = a1;
  *(f4*)&gL[2][4 * tid] = a2;
  *(f4*)&gL[3][4 * tid] = a3;
}

// proj GEMV (W1 or W2): thread t owns col t; outputs aq[batch]
__device__ __forceinline__ void gemv_proj(const float* __restrict__ WT,
                                          const float hL[4][512], float aq[4], int tid) {
  aq[0] = aq[1] = aq[2] = aq[3] = 0.f;
#pragma unroll 2
  for (int k4 = 0; k4 < 128; ++k4) {
    const f4 hv0 = *(const f4*)&hL[0][k4 * 4];
    const f4 hv1 = *(const f4*)&hL[1][k4 * 4];
    const f4 hv2 = *(const f4*)&hL[2][k4 * 4];
    const f4 hv3 = *(const f4*)&hL[3][k4 * 4];
#pragma unroll
    for (int kk = 0; kk < 4; ++kk) {
      const float w = WT[(size_t)(k4 * 4 + kk) * 512 + tid];
      aq[0] = fmaf(hv0[kk], w, aq[0]);
      aq[1] = fmaf(hv1[kk], w, aq[1]);
      aq[2] = fmaf(hv2[kk], w, aq[2]);
      aq[3] = fmaf(hv3[kk], w, aq[3]);
    }
  }
}

// LSTM cell: thread t -> batch i = t>>7, cells u0..u0+3
__device__ __forceinline__ void cell_update(const float gL[4][2048], float hL[4][512],
                                            float cL[4][512], const float* __restrict__ A,
                                            const float* __restrict__ D, float x, int i,
                                            int u0) {
  const f4 sgi = *(const f4*)&gL[i][u0];
  const f4 sgf = *(const f4*)&gL[i][512 + u0];
  const f4 sgg = *(const f4*)&gL[i][1024 + u0];
  const f4 sgo = *(const f4*)&gL[i][1536 + u0];
  f4 hnew, cnew;
#pragma unroll
  for (int c = 0; c < 4; ++c) {
    const int r = u0 + c;
    const float pi = fmaf(x, A[r], D[r]) + sgi[c];
    const float pf = fmaf(x, A[512 + r], D[512 + r]) + sgf[c];
    const float pg = fmaf(x, A[1024 + r], D[1024 + r]) + sgg[c];
    const float po = fmaf(x, A[1536 + r], D[1536 + r]) + sgo[c];
    const float gi = fast_sigmoid(pi);
    const float gf = fast_sigmoid(pf);
    const float gg = fast_tanh(pg);
    const float go = fast_sigmoid(po);
    const float cn = gf * cL[i][r] + gi * gg;
    cnew[c] = cn;
    hnew[c] = go * fast_tanh(cn);
  }
  *(f4*)&cL[i][u0] = cnew;
  *(f4*)&hL[i][u0] = hnew;
}

// ---------------- encoder: 128 independent blocks x 4 batches ----------------
__global__ __launch_bounds__(512, 1) void k_encoder(
    const float* __restrict__ in_seq, const float* __restrict__ WTG,
    const float* __restrict__ W1T, const float* __restrict__ A,
    const float* __restrict__ D, const float* __restrict__ w1b,
    float* __restrict__ ep, float* __restrict__ hc) {
  __shared__ __align__(16) float hL[4][512];
  __shared__ __align__(16) float cL[4][512];
  __shared__ __align__(16) float gL[4][2048];
  __shared__ float lds_pad[9216];  // force 1 block/CU (84 KB total)
  const int tid = threadIdx.x, blk = blockIdx.x;
  const int b0 = blk * 4;
#pragma unroll
  for (int e = 0; e < 4; ++e) {
    ((float*)hL)[tid + e * 512] = 0.f;
    ((float*)cL)[tid + e * 512] = 0.f;
  }
  if (blockDim.x > 4096) lds_pad[0] = 1.f;  // opaque-false: keeps pad allocated
  __syncthreads();
  const f4* wg = (const f4*)WTG + tid;
  const int ci = tid >> 7, u0 = (tid & 127) * 4;
  for (int s = 0; s < NL; ++s) {
    gemv_gates(wg, hL, gL, tid);
    __syncthreads();
    cell_update(gL, hL, cL, A, D, in_seq[(size_t)(b0 + ci) * NL + s], ci, u0);
    __syncthreads();
    // ep[b][s][:] = h_s @ W1^T + b1
    float aq[4];
    gemv_proj(W1T, hL, aq, tid);
    const float bq = w1b[tid];
#pragma unroll
    for (int i = 0; i < 4; ++i)
      ep[((size_t)(b0 + i) * NL + s) * NH + tid] = aq[i] + bq;
  }
#pragma unroll
  for (int e = 0; e < 4; ++e) {
    hc[(size_t)blk * 4096 + tid + e * 512] = ((float*)hL)[tid + e * 512];
    hc[(size_t)blk * 4096 + 2048 + tid + e * 512] = ((float*)cL)[tid + e * 512];
  }
}

// ---------------- decoder: 128 independent blocks x 4 batches ----------------
__global__ __launch_bounds__(512, 1) void k_decoder(
    const float* __restrict__ in_seq, const float* __restrict__ WTG,
    const float* __restrict__ W2T, const float* __restrict__ A,
    const float* __restrict__ D, const float* __restrict__ w2b,
    const float* __restrict__ ep, const float* __restrict__ vW,
    const float* __restrict__ vb, const float* __restrict__ hc,
    float* __restrict__ out_attn, float* __restrict__ out_ptr) {
  __shared__ __align__(16) float hL[4][512];
  __shared__ __align__(16) float cL[4][512];
  __shared__ __align__(16) float gL[4][2048];
  __shared__ __align__(16) float qL[4][512];
  __shared__ float ush[4][256];
  __shared__ float nxtL[4];
  __shared__ float lds_pad[5120];  // force 1 block/CU (~84 KB total)
  const int tid = threadIdx.x, blk = blockIdx.x;
  const int b0 = blk * 4;
#pragma unroll
  for (int e = 0; e < 4; ++e) {
    ((float*)hL)[tid + e * 512] = hc[(size_t)blk * 4096 + tid + e * 512];
    ((float*)cL)[tid + e * 512] = hc[(size_t)blk * 4096 + 2048 + tid + e * 512];
  }
  if (tid < 4) nxtL[tid] = -1.0f;  // SOS
  if (blockDim.x > 4096) lds_pad[0] = 1.f;
  __syncthreads();
  const f4* wg = (const f4*)WTG + tid;
  const int ci = tid >> 7, u0 = (tid & 127) * 4;
  const int wv = tid >> 6, lane = tid & 63;
  for (int s = 0; s < NL; ++s) {
    // P1: gates + LSTM (x = pointer feedback, block-local)
    gemv_gates(wg, hL, gL, tid);
    __syncthreads();
    cell_update(gL, hL, cL, A, D, nxtL[ci], ci, u0);
    __syncthreads();
    // P2: q = h @ W2^T + b2 (block-local)
    {
      float aq[4];
      gemv_proj(W2T, hL, aq, tid);
      const float bq = w2b[tid];
#pragma unroll
      for (int i = 0; i < 4; ++i) qL[i][tid] = aq[i] + bq;
    }
    __syncthreads();
    // P3a: u[l] = v . tanh(ep[b][l] + q), wave (i=wv>>1, half=wv&1) does 128 rows
    {
      const int ai = wv >> 1, hf = wv & 1;
      const f4 q0 = *(const f4*)&qL[ai][8 * lane];
      const f4 q1 = *(const f4*)&qL[ai][8 * lane + 4];
      const f4* vW4 = (const f4*)vW;
      const f4 v0 = vW4[2 * lane], v1 = vW4[2 * lane + 1];
      const float vbs = vb[0];
      const float* epb = ep + ((size_t)(b0 + ai) * NL + hf * 128) * NH + 8 * lane;
      for (int li = 0; li < 128; li += 2) {
        const f4 ea0 = *(const f4*)(epb + (size_t)li * NH);
        const f4 ea1 = *(const f4*)(epb + (size_t)li * NH + 4);
        const f4 eb0 = *(const f4*)(epb + (size_t)(li + 1) * NH);
        const f4 eb1 = *(const f4*)(epb + (size_t)(li + 1) * NH + 4);
        float sa = v0.x * fast_tanh(ea0.x + q0.x);
        sa = fmaf(v0.y, fast_tanh(ea0.y + q0.y), sa);
        sa = fmaf(v0.z, fast_tanh(ea0.z + q0.z), sa);
        sa = fmaf(v0.w, fast_tanh(ea0.w + q0.w), sa);
        sa = fmaf(v1.x, fast_tanh(ea1.x + q1.x), sa);
        sa = fmaf(v1.y, fast_tanh(ea1.y + q1.y), sa);
        sa = fmaf(v1.z, fast_tanh(ea1.z + q1.z), sa);
        sa = fmaf(v1.w, fast_tanh(ea1.w + q1.w), sa);
        float sb = v0.x * fast_tanh(eb0.x + q0.x);
        sb = fmaf(v0.y, fast_tanh(eb0.y + q0.y), sb);
        sb = fmaf(v0.z, fast_tanh(eb0.z + q0.z), sb);
        sb = fmaf(v0.w, fast_tanh(eb0.w + q0.w), sb);
        sb = fmaf(v1.x, fast_tanh(eb1.x + q1.x), sb);
        sb = fmaf(v1.y, fast_tanh(eb1.y + q1.y), sb);
        sb = fmaf(v1.z, fast_tanh(eb1.z + q1.z), sb);
        sb = fmaf(v1.w, fast_tanh(eb1.w + q1.w), sb);
#pragma unroll
        for (int d = 1; d < 64; d <<= 1) {
          sa += __shfl_xor(sa, d, 64);
          sb += __shfl_xor(sb, d, 64);
        }
        if (lane == 0) {
          ush[ai][hf * 128 + li] = sa + vbs;
          ush[ai][hf * 128 + li + 1] = sb + vbs;
        }
      }
    }
    __syncthreads();
    // P3b: log_softmax + argmax + feedback; even waves, one per batch
    if ((wv & 1) == 0) {
      const int ai = wv >> 1;
      const size_t bb = (size_t)(b0 + ai);
      float m = -3.4e38f;
      int idx = 0;
#pragma unroll
      for (int r = 0; r < 4; ++r) {  // ascending l within lane
        const int l = lane * 4 + r;
        const float uu = ush[ai][l];
        if (uu > m) { m = uu; idx = l; }
      }
#pragma unroll
      for (int d = 1; d < 64; d <<= 1) {  // tie -> smaller index
        const float om = __shfl_xor(m, d, 64);
        const int oi = __shfl_xor(idx, d, 64);
        if (om > m || (om == m && oi < idx)) { m = om; idx = oi; }
      }
      float se = 0.f;
#pragma unroll
      for (int r = 0; r < 4; ++r) se += __expf(ush[ai][lane * 4 + r] - m);
#pragma unroll
      for (int d = 1; d < 64; d <<= 1) se += __shfl_xor(se, d, 64);
      if (lane == 0) {
        out_ptr[bb * NL + s] = (float)idx;
        nxtL[ai] = in_seq[bb * NL + idx];  // F=1
      }
      const float lse = logf(se);
      f4 o;
#pragma unroll
      for (int r = 0; r < 4; ++r) o[r] = ush[ai][lane * 4 + r] - m - lse;
      *(f4*)(out_attn + (bb * NL + s) * NL + 4 * lane) = o;
    }
    __syncthreads();
  }
}

extern "C" void kernel_launch(void* const* d_in, const int* in_sizes, int n_in,
                              void* d_out, int out_size, void* d_ws, size_t ws_size,
                              hipStream_t stream) {
  const float* in_seq   = (const float*)d_in[0];
  const float* enc_embW = (const float*)d_in[1];
  const float* enc_embB = (const float*)d_in[2];
  const float* enc_Wih  = (const float*)d_in[3];
  const float* enc_Whh  = (const float*)d_in[4];
  const float* enc_bih  = (const float*)d_in[5];
  const float* enc_bhh  = (const float*)d_in[6];
  const float* dec_embW = (const float*)d_in[7];
  const float* dec_embB = (const float*)d_in[8];
  const float* dec_Wih  = (const float*)d_in[9];
  const float* dec_Whh  = (const float*)d_in[10];
  const float* dec_bih  = (const float*)d_in[11];
  const float* dec_bhh  = (const float*)d_in[12];
  const float* W1_W     = (const float*)d_in[13];
  const float* W1_b     = (const float*)d_in[14];
  const float* W2_W     = (const float*)d_in[15];
  const float* W2_b     = (const float*)d_in[16];
  const float* v_W      = (const float*)d_in[17];
  const float* v_b      = (const float*)d_in[18];

  float* wsf = (float*)d_ws;
  float* out_attn = (float*)d_out;
  float* out_ptr  = out_attn + (size_t)NB * NL * NL;

  // ---- prep: weight transposes + A/D folds (no memsets, no barrier state) ----
  k_transpose<<<4096, 256, 0, stream>>>(enc_Whh, wsf + WTG_ENC, 11, 9);
  k_transpose<<<4096, 256, 0, stream>>>(dec_Whh, wsf + WTG_DEC, 11, 9);
  k_transpose<<<1024, 256, 0, stream>>>(W1_W, wsf + W1T_OFF, 9, 9);
  k_transpose<<<1024, 256, 0, stream>>>(W2_W, wsf + W2T_OFF, 9, 9);
  k_prep_ad<<<512, 256, 0, stream>>>(enc_Wih, enc_embW, enc_embB, enc_bih, enc_bhh,
                                     wsf + A_ENC, wsf + D_ENC);
  k_prep_ad<<<512, 256, 0, stream>>>(dec_Wih, dec_embW, dec_embB, dec_bih, dec_bhh,
                                     wsf + A_DEC, wsf + D_DEC);

  // ---- encoder + decoder: batch-partitioned, zero inter-block communication ----
  k_encoder<<<NBLKS, 512, 0, stream>>>(in_seq, wsf + WTG_ENC, wsf + W1T_OFF, wsf + A_ENC,
                                       wsf + D_ENC, W1_b, wsf + EP_OFF, wsf + HC_OFF);
  k_decoder<<<NBLKS, 512, 0, stream>>>(in_seq, wsf + WTG_DEC, wsf + W2T_OFF, wsf + A_DEC,
                                       wsf + D_DEC, W2_b, wsf + EP_OFF, v_W, v_b,
                                       wsf + HC_OFF, out_attn, out_ptr);
}